// Round 6
// baseline (2045.994 us; speedup 1.0000x reference)
//
#include <hip/hip_runtime.h>

#define DD 64
typedef unsigned int uint32;
typedef unsigned short ushort16;
typedef short bf16x8 __attribute__((ext_vector_type(8)));
typedef float f32x4 __attribute__((ext_vector_type(4)));

__device__ __forceinline__ ushort16 f2bf(float x) {
    uint32 u = __float_as_uint(x);
    uint32 r = (u + 0x7FFFu + ((u >> 16) & 1u)) >> 16;
    return (ushort16)r;
}
__device__ __forceinline__ float bf2f(ushort16 h) {
    return __uint_as_float(((uint32)h) << 16);
}
__device__ __forceinline__ uint32 packsplit(float x) {
    ushort16 hi = f2bf(x);
    ushort16 lo = f2bf(x - bf2f(hi));
    return ((uint32)hi << 16) | (uint32)lo;
}

__device__ __forceinline__ void split8f(const float4& a, const float4& b, bf16x8& ah, bf16x8& al) {
    float xs[8] = {a.x, a.y, a.z, a.w, b.x, b.y, b.z, b.w};
#pragma unroll
    for (int i = 0; i < 8; ++i) {
        ushort16 hi = f2bf(xs[i]);
        ah[i] = (short)hi;
        al[i] = (short)f2bf(xs[i] - bf2f(hi));
    }
}
__device__ __forceinline__ void unpack8(const uint4& a, const uint4& b, bf16x8& ah, bf16x8& al) {
    uint32 us[8] = {a.x, a.y, a.z, a.w, b.x, b.y, b.z, b.w};
#pragma unroll
    for (int i = 0; i < 8; ++i) {
        ah[i] = (short)(us[i] >> 16);
        al[i] = (short)(us[i] & 0xFFFFu);
    }
}

// 1 k-step (K=32) split-bf16 MFMA over 4 m x 4 n tiles (3-term)
__device__ __forceinline__ void mfma_ks(const unsigned short* __restrict__ wks, int l,
                                        const bf16x8* ah, const bf16x8* al, f32x4 (*acc)[4]) {
#pragma unroll
    for (int tt = 0; tt < 4; ++tt) {
        bf16x8 bh = *(const bf16x8*)(wks + ((size_t)(tt * 2 + 0) * 64 + l) * 8);
        bf16x8 bl = *(const bf16x8*)(wks + ((size_t)(tt * 2 + 1) * 64 + l) * 8);
#pragma unroll
        for (int m = 0; m < 4; ++m) {
            acc[m][tt] = __builtin_amdgcn_mfma_f32_16x16x32_bf16(ah[m], bh, acc[m][tt], 0, 0, 0);
            acc[m][tt] = __builtin_amdgcn_mfma_f32_16x16x32_bf16(ah[m], bl, acc[m][tt], 0, 0, 0);
            acc[m][tt] = __builtin_amdgcn_mfma_f32_16x16x32_bf16(al[m], bh, acc[m][tt], 0, 0, 0);
        }
    }
}
// hi-only A variant (2-term)
__device__ __forceinline__ void mfma_ks_hi(const unsigned short* __restrict__ wks, int l,
                                           const bf16x8* ah, f32x4 (*acc)[4]) {
#pragma unroll
    for (int tt = 0; tt < 4; ++tt) {
        bf16x8 bh = *(const bf16x8*)(wks + ((size_t)(tt * 2 + 0) * 64 + l) * 8);
        bf16x8 bl = *(const bf16x8*)(wks + ((size_t)(tt * 2 + 1) * 64 + l) * 8);
#pragma unroll
        for (int m = 0; m < 4; ++m) {
            acc[m][tt] = __builtin_amdgcn_mfma_f32_16x16x32_bf16(ah[m], bh, acc[m][tt], 0, 0, 0);
            acc[m][tt] = __builtin_amdgcn_mfma_f32_16x16x32_bf16(ah[m], bl, acc[m][tt], 0, 0, 0);
        }
    }
}
// single-m variant
__device__ __forceinline__ void mfma_ks1(const unsigned short* __restrict__ wks, int l,
                                         bf16x8 ah, bf16x8 al, f32x4* acc) {
#pragma unroll
    for (int tt = 0; tt < 4; ++tt) {
        bf16x8 bh = *(const bf16x8*)(wks + ((size_t)(tt * 2 + 0) * 64 + l) * 8);
        bf16x8 bl = *(const bf16x8*)(wks + ((size_t)(tt * 2 + 1) * 64 + l) * 8);
        acc[tt] = __builtin_amdgcn_mfma_f32_16x16x32_bf16(ah, bh, acc[tt], 0, 0, 0);
        acc[tt] = __builtin_amdgcn_mfma_f32_16x16x32_bf16(ah, bl, acc[tt], 0, 0, 0);
        acc[tt] = __builtin_amdgcn_mfma_f32_16x16x32_bf16(al, bh, acc[tt], 0, 0, 0);
    }
}

// ---------------- CSR build ----------------
__global__ void zero_counts_kernel(int* __restrict__ counts, int N) {
    int i = blockIdx.x * blockDim.x + threadIdx.x;
    if (i < N) counts[i] = 0;
}
__global__ void hist_kernel(const int* __restrict__ recv, int* __restrict__ counts, int E) {
    int i = blockIdx.x * blockDim.x + threadIdx.x;
    if (i < E) atomicAdd(&counts[recv[i]], 1);
}
__global__ __launch_bounds__(1024) void scan_kernel(const int* __restrict__ counts,
                                                    int* __restrict__ offs,
                                                    int* __restrict__ cursor, int N) {
    __shared__ int sm[1024];
    __shared__ int carryS;
    int t = threadIdx.x;
    if (t == 0) carryS = 0;
    __syncthreads();
    for (int base = 0; base < N; base += 4096) {
        int idx = base + t * 4;
        int x0 = (idx + 0 < N) ? counts[idx + 0] : 0;
        int x1 = (idx + 1 < N) ? counts[idx + 1] : 0;
        int x2 = (idx + 2 < N) ? counts[idx + 2] : 0;
        int x3 = (idx + 3 < N) ? counts[idx + 3] : 0;
        int s1 = x0 + x1, s2 = s1 + x2, s3 = s2 + x3;
        sm[t] = s3;
        __syncthreads();
        for (int d = 1; d < 1024; d <<= 1) {
            int v = (t >= d) ? sm[t - d] : 0;
            __syncthreads();
            sm[t] += v;
            __syncthreads();
        }
        int excl = sm[t] - s3 + carryS;
        if (idx < N)     { offs[idx]     = excl;      cursor[idx]     = excl; }
        if (idx + 1 < N) { offs[idx + 1] = excl + x0; cursor[idx + 1] = excl + x0; }
        if (idx + 2 < N) { offs[idx + 2] = excl + s1; cursor[idx + 2] = excl + s1; }
        if (idx + 3 < N) { offs[idx + 3] = excl + s2; cursor[idx + 3] = excl + s2; }
        int chunkTotal = sm[1023];
        __syncthreads();
        if (t == 0) carryS += chunkTotal;
        __syncthreads();
    }
    if (t == 0) offs[N] = carryS;
}
__global__ void scatter_kernel(const int* __restrict__ recv, int* __restrict__ cursor,
                               int* __restrict__ perm, int E) {
    int i = blockIdx.x * blockDim.x + threadIdx.x;
    if (i < E) {
        int p = atomicAdd(&cursor[recv[i]], 1);
        perm[p] = i;
    }
}

// ---------------- prep: fold g @ W1[g-rows] into effective layer-1 biases --------------
__global__ void prep_bias_kernel(const float* __restrict__ g,
                                 const float* __restrict__ We1, const float* __restrict__ be1,
                                 const float* __restrict__ Wn1, const float* __restrict__ bn1,
                                 float* __restrict__ be1e, float* __restrict__ bn1e) {
    int j = threadIdx.x;
    float a = be1[j];
    float b = bn1[j];
    for (int k = 0; k < DD; ++k) {
        float gk = g[k];
        a = fmaf(gk, We1[(192 + k) * DD + j], a);
        b = fmaf(gk, Wn1[(128 + k) * DD + j], b);
    }
    be1e[j] = a;
    bn1e[j] = b;
}

// ---------------- prep: split nodes fp32 -> packed (hi<<16)|lo ---------------
__global__ void prep_nodes_kernel(const float* __restrict__ src, uint32* __restrict__ dst,
                                  int total) {
    int i = blockIdx.x * blockDim.x + threadIdx.x;
    if (i < total) dst[i] = packsplit(src[i]);
}

// ---------------- prep: weights -> hi/lo bf16, pre-swizzled into B-fragment order ------
__device__ __forceinline__ void prep_pack(const float* __restrict__ W, int nks,
                                          unsigned short* __restrict__ dst, int tid) {
    if (tid < nks * 2048) {
        int i = tid & 7, lane = (tid >> 3) & 63, tt = (tid >> 9) & 3, ks = tid >> 11;
        int k = ks * 32 + (lane >> 4) * 8 + i;
        int n = tt * 16 + (lane & 15);
        float x = W[k * DD + n];
        ushort16 hi = f2bf(x);
        ushort16 lo = f2bf(x - bf2f(hi));
        dst[(((ks * 4 + tt) * 2 + 0) * 64 + lane) * 8 + i] = hi;
        dst[(((ks * 4 + tt) * 2 + 1) * 64 + lane) * 8 + i] = lo;
    }
}
__global__ void prep_weights_kernel(const float* __restrict__ We1, const float* __restrict__ We2,
                                    const float* __restrict__ Wn1, const float* __restrict__ Wn2,
                                    unsigned short* __restrict__ we1p, unsigned short* __restrict__ we2p,
                                    unsigned short* __restrict__ wn1p, unsigned short* __restrict__ wn2p) {
    int tid = blockIdx.x * blockDim.x + threadIdx.x;
    prep_pack(We1, 6, we1p, tid);
    prep_pack(We2, 2, we2p, tid);
    prep_pack(Wn1, 4, wn1p, tid);
    prep_pack(Wn2, 2, wn2p, tid);
}

// ======== edge update, receiver-sorted; IN_BF: read seq bf16 ws; OUT_F32: scatter fp32 ==
template<int IN_BF, int OUT_F32>
__global__ __launch_bounds__(256, 3) void edge_kernel_t(
    const float* __restrict__ edges_f32, const unsigned short* __restrict__ edges_bf,
    const uint32* __restrict__ nodes_pk,
    const int* __restrict__ senders, const int* __restrict__ receivers,
    const int* __restrict__ perm,
    const unsigned short* __restrict__ w1, const float* __restrict__ b1,
    const unsigned short* __restrict__ w2, const float* __restrict__ b2,
    float* __restrict__ eout_f32, unsigned short* __restrict__ eout_bf,
    float* __restrict__ received, float* __restrict__ agg_e, int E)
{
    __shared__ int PE[4][64];
    __shared__ int SID[4][64];
    __shared__ int RID[4][64];
    __shared__ float PS[4][64];
    __shared__ __align__(16) char HB[4][4096];

    const int t = threadIdx.x;
    const int w = t >> 6, l = t & 63;
    const int lm = l & 15, kq = l >> 4;
    const int base = (blockIdx.x << 8) + (w << 6);

    {
        int pos = base + l;
        int pe = perm[min(pos, E - 1)];
        PE[w][l] = pe;
        SID[w][l] = senders[pe];
        RID[w][l] = receivers[pe];
    }

    int pe_m[4], sid_m[4], rid_m[4];
#pragma unroll
    for (int m = 0; m < 4; ++m) {
        pe_m[m]  = PE[w][(m << 4) + lm];
        sid_m[m] = SID[w][(m << 4) + lm];
        rid_m[m] = RID[w][(m << 4) + lm];
    }

    // ---- issue edges-chunk loads ----
    float4 re[4][4];
    uint4 rbe[4][2];
    if (IN_BF) {
#pragma unroll
        for (int m = 0; m < 4; ++m) {
            int row = min(base + (m << 4) + lm, E - 1);
            const unsigned short* p = edges_bf + (size_t)row * DD;
            rbe[m][0] = *(const uint4*)(p + kq * 8);
            rbe[m][1] = *(const uint4*)(p + 32 + kq * 8);
        }
    } else {
#pragma unroll
        for (int m = 0; m < 4; ++m) {
            const float* p = edges_f32 + (size_t)pe_m[m] * DD + kq * 8;
            re[m][0] = *(const float4*)(p);
            re[m][1] = *(const float4*)(p + 4);
            re[m][2] = *(const float4*)(p + 32);
            re[m][3] = *(const float4*)(p + 36);
        }
    }
    // ---- issue sender-chunk loads ----
    uint4 rs[4][4];
#pragma unroll
    for (int m = 0; m < 4; ++m) {
        const uint32* p = nodes_pk + (size_t)sid_m[m] * DD + kq * 8;
        rs[m][0] = *(const uint4*)(p);
        rs[m][1] = *(const uint4*)(p + 4);
        rs[m][2] = *(const uint4*)(p + 32);
        rs[m][3] = *(const uint4*)(p + 36);
    }

    f32x4 acc[4][4];
#pragma unroll
    for (int tt = 0; tt < 4; ++tt) {
        float b = b1[tt * 16 + lm];
#pragma unroll
        for (int m = 0; m < 4; ++m) { acc[m][tt][0] = b; acc[m][tt][1] = b; acc[m][tt][2] = b; acc[m][tt][3] = b; }
    }

    // ---- process edges chunk (ks 0,1) ----
    if (IN_BF) {
#pragma unroll
        for (int ks2 = 0; ks2 < 2; ++ks2) {
            bf16x8 ah[4];
#pragma unroll
            for (int m = 0; m < 4; ++m) ah[m] = *(bf16x8*)&rbe[m][ks2];
            mfma_ks_hi(w1 + (size_t)ks2 * 4096, l, ah, acc);
        }
    } else {
#pragma unroll
        for (int ks2 = 0; ks2 < 2; ++ks2) {
            bf16x8 ah[4], al[4];
#pragma unroll
            for (int m = 0; m < 4; ++m) split8f(re[m][ks2 * 2], re[m][ks2 * 2 + 1], ah[m], al[m]);
            mfma_ks(w1 + (size_t)ks2 * 4096, l, ah, al, acc);
        }
    }

    // ---- issue receiver-chunk loads (sorted -> cache-hot) ----
    uint4 rr[4][4];
#pragma unroll
    for (int m = 0; m < 4; ++m) {
        const uint32* p = nodes_pk + (size_t)rid_m[m] * DD + kq * 8;
        rr[m][0] = *(const uint4*)(p);
        rr[m][1] = *(const uint4*)(p + 4);
        rr[m][2] = *(const uint4*)(p + 32);
        rr[m][3] = *(const uint4*)(p + 36);
    }

    // ---- sender chunk (ks 2,3) ----
#pragma unroll
    for (int ks2 = 0; ks2 < 2; ++ks2) {
        bf16x8 ah[4], al[4];
#pragma unroll
        for (int m = 0; m < 4; ++m) unpack8(rs[m][ks2 * 2], rs[m][ks2 * 2 + 1], ah[m], al[m]);
        mfma_ks(w1 + (size_t)(2 + ks2) * 4096, l, ah, al, acc);
    }
    // ---- receiver chunk (ks 4,5) ----
#pragma unroll
    for (int ks2 = 0; ks2 < 2; ++ks2) {
        bf16x8 ah[4], al[4];
#pragma unroll
        for (int m = 0; m < 4; ++m) unpack8(rr[m][ks2 * 2], rr[m][ks2 * 2 + 1], ah[m], al[m]);
        mfma_ks(w1 + (size_t)(4 + ks2) * 4096, l, ah, al, acc);
    }

    // ---- per m-tile: h->LDS, GEMM2, C stage, store + segmented received atomics ----
    float b2v[4];
#pragma unroll
    for (int tt = 0; tt < 4; ++tt) b2v[tt] = b2[tt * 16 + lm];
    float sreg[4] = {0.f, 0.f, 0.f, 0.f};
    char* hh = &HB[w][0];
    char* hl = &HB[w][2048];

#pragma unroll
    for (int m = 0; m < 4; ++m) {
#pragma unroll
        for (int tt = 0; tt < 4; ++tt)
#pragma unroll
            for (int r = 0; r < 4; ++r) {
                int row = (kq << 2) + r;
                int col = (tt << 4) + lm;
                float hv = fmaxf(acc[m][tt][r], 0.f);
                ushort16 hi = f2bf(hv);
                ushort16 lo = f2bf(hv - bf2f(hi));
                int boff = (row << 7) + ((((col >> 3) ^ (row & 7)) & 7) << 4) + ((col & 7) << 1);
                *(unsigned short*)(hh + boff) = hi;
                *(unsigned short*)(hl + boff) = lo;
            }

        f32x4 acc2[4];
#pragma unroll
        for (int tt = 0; tt < 4; ++tt) { acc2[tt][0] = b2v[tt]; acc2[tt][1] = b2v[tt]; acc2[tt][2] = b2v[tt]; acc2[tt][3] = b2v[tt]; }
#pragma unroll
        for (int ks = 0; ks < 2; ++ks) {
            int boff = (lm << 7) + ((((kq + ks * 4) ^ (lm & 7)) & 7) << 4);
            bf16x8 ah = *(const bf16x8*)(hh + boff);
            bf16x8 al = *(const bf16x8*)(hl + boff);
            mfma_ks1(w2 + (size_t)ks * 4096, l, ah, al, acc2);
        }

#pragma unroll
        for (int tt = 0; tt < 4; ++tt)
#pragma unroll
            for (int r = 0; r < 4; ++r) {
                int rowp = base + (m << 4) + (kq << 2) + r;
                if (rowp < E) sreg[tt] += acc2[tt][r];
            }

        // stage C fp32 swizzled
#pragma unroll
        for (int tt = 0; tt < 4; ++tt)
#pragma unroll
            for (int r = 0; r < 4; ++r) {
                int row = (kq << 2) + r;
                int col = (tt << 4) + lm;
                int boff = (row << 8) + ((((col >> 2) ^ (row & 15)) & 15) << 4) + ((col & 3) << 2);
                *(float*)(&HB[w][0] + boff) = acc2[tt][r];
            }

        // readback 16 consecutive cols [kq*16, kq*16+16) of row lm
        {
            int rowp = base + (m << 4) + lm;
            float4 vv[4];
#pragma unroll
            for (int jj = 0; jj < 4; ++jj) {
                int slot = (4 * kq + jj) ^ (lm & 15);
                vv[jj] = *(float4*)(&HB[w][0] + (lm << 8) + (slot << 4));
            }
            if (rowp < E) {
                if (OUT_F32) {
                    float4* dst = (float4*)(eout_f32 + (size_t)pe_m[m] * DD);
#pragma unroll
                    for (int jj = 0; jj < 4; ++jj) dst[kq * 4 + jj] = vv[jj];
                } else {
                    uint4 o0, o1;
                    o0.x = (uint32)f2bf(vv[0].x) | ((uint32)f2bf(vv[0].y) << 16);
                    o0.y = (uint32)f2bf(vv[0].z) | ((uint32)f2bf(vv[0].w) << 16);
                    o0.z = (uint32)f2bf(vv[1].x) | ((uint32)f2bf(vv[1].y) << 16);
                    o0.w = (uint32)f2bf(vv[1].z) | ((uint32)f2bf(vv[1].w) << 16);
                    o1.x = (uint32)f2bf(vv[2].x) | ((uint32)f2bf(vv[2].y) << 16);
                    o1.y = (uint32)f2bf(vv[2].z) | ((uint32)f2bf(vv[2].w) << 16);
                    o1.z = (uint32)f2bf(vv[3].x) | ((uint32)f2bf(vv[3].y) << 16);
                    o1.w = (uint32)f2bf(vv[3].z) | ((uint32)f2bf(vv[3].w) << 16);
                    unsigned short* dst = eout_bf + (size_t)rowp * DD + kq * 16;
                    *(uint4*)(dst) = o0;
                    *(uint4*)(dst + 8) = o1;
                }
            }
        }

        // segmented sum over 16 sorted rows -> received atomics (lane = col)
        {
            float run = 0.f;
#pragma unroll
            for (int r = 0; r < 16; ++r) {
                int rowp = base + (m << 4) + r;
                if (rowp < E) {
                    int boff = (r << 8) + ((((l >> 2) ^ (r & 15)) & 15) << 4) + ((l & 3) << 2);
                    float v = *(const float*)(&HB[w][0] + boff);
                    int rid = RID[w][(m << 4) + r];
                    run += v;
                    bool flush;
                    if (r == 15) flush = true;
                    else flush = (rowp + 1 >= E) || (RID[w][(m << 4) + r + 1] != rid);
                    if (flush) {
                        atomicAdd(&received[(size_t)rid * DD + l], run);
                        run = 0.f;
                    }
                }
            }
        }
    }

#pragma unroll
    for (int tt = 0; tt < 4; ++tt) {
        float s = sreg[tt];
        s += __shfl_xor(s, 16, 64);
        s += __shfl_xor(s, 32, 64);
        if (l < 16) PS[w][tt * 16 + l] = s;
    }
    __syncthreads();
    if (t < 64) {
        float s = PS[0][t] + PS[1][t] + PS[2][t] + PS[3][t];
        atomicAdd(agg_e + t, s);
    }
}

// ======================= node update: 256 nodes/block, 64/wave =========================
__global__ __launch_bounds__(256, 2) void node_kernel_mfma(
    const uint32* __restrict__ nodes_pk, const float* __restrict__ received,
    const unsigned short* __restrict__ w1, const float* __restrict__ b1,
    const unsigned short* __restrict__ w2, const float* __restrict__ b2,
    float* __restrict__ nodes_out, uint32* __restrict__ nodes_pk_out, int write_pk,
    float* __restrict__ agg_n, int N)
{
    __shared__ unsigned short HB[4][4][2][1024];
    __shared__ float PS[4][64];

    const int t = threadIdx.x;
    const int w = t >> 6, l = t & 63;
    const int lm = l & 15, kq = l >> 4;
    const int base = (blockIdx.x << 8) + (w << 6);

    int gi[4];
#pragma unroll
    for (int m = 0; m < 4; ++m) gi[m] = min(base + (m << 4) + lm, N - 1);

    uint4 rn[4][4];
#pragma unroll
    for (int m = 0; m < 4; ++m) {
        const uint32* p = nodes_pk + (size_t)gi[m] * DD + kq * 8;
        rn[m][0] = *(const uint4*)(p);
        rn[m][1] = *(const uint4*)(p + 4);
        rn[m][2] = *(const uint4*)(p + 32);
        rn[m][3] = *(const uint4*)(p + 36);
    }
    float4 rc[4][4];
#pragma unroll
    for (int m = 0; m < 4; ++m) {
        const float* p = received + (size_t)gi[m] * DD + kq * 8;
        rc[m][0] = *(const float4*)(p);
        rc[m][1] = *(const float4*)(p + 4);
        rc[m][2] = *(const float4*)(p + 32);
        rc[m][3] = *(const float4*)(p + 36);
    }

    f32x4 acc[4][4];
#pragma unroll
    for (int tt = 0; tt < 4; ++tt) {
        float b = b1[tt * 16 + lm];
#pragma unroll
        for (int m = 0; m < 4; ++m) { acc[m][tt][0] = b; acc[m][tt][1] = b; acc[m][tt][2] = b; acc[m][tt][3] = b; }
    }

#pragma unroll
    for (int ks2 = 0; ks2 < 2; ++ks2) {
        bf16x8 ah[4], al[4];
#pragma unroll
        for (int m = 0; m < 4; ++m) unpack8(rn[m][ks2 * 2], rn[m][ks2 * 2 + 1], ah[m], al[m]);
        mfma_ks(w1 + (size_t)ks2 * 4096, l, ah, al, acc);
    }
#pragma unroll
    for (int ks2 = 0; ks2 < 2; ++ks2) {
        bf16x8 ah[4], al[4];
#pragma unroll
        for (int m = 0; m < 4; ++m) split8f(rc[m][ks2 * 2], rc[m][ks2 * 2 + 1], ah[m], al[m]);
        mfma_ks(w1 + (size_t)(2 + ks2) * 4096, l, ah, al, acc);
    }

#pragma unroll
    for (int m = 0; m < 4; ++m) {
        char* hh = (char*)&HB[w][m][0][0];
        char* hl = (char*)&HB[w][m][1][0];
#pragma unroll
        for (int tt = 0; tt < 4; ++tt)
#pragma unroll
            for (int r = 0; r < 4; ++r) {
                int row = (kq << 2) + r;
                int col = (tt << 4) + lm;
                float hv = fmaxf(acc[m][tt][r], 0.f);
                ushort16 hi = f2bf(hv);
                ushort16 lo = f2bf(hv - bf2f(hi));
                int boff = (row << 7) + ((((col >> 3) ^ (row & 7)) & 7) << 4) + ((col & 7) << 1);
                *(unsigned short*)(hh + boff) = hi;
                *(unsigned short*)(hl + boff) = lo;
            }
    }

    f32x4 acc2[4][4];
#pragma unroll
    for (int tt = 0; tt < 4; ++tt) {
        float b = b2[tt * 16 + lm];
#pragma unroll
        for (int m = 0; m < 4; ++m) { acc2[m][tt][0] = b; acc2[m][tt][1] = b; acc2[m][tt][2] = b; acc2[m][tt][3] = b; }
    }
#pragma unroll
    for (int ks = 0; ks < 2; ++ks) {
        bf16x8 ah[4], al[4];
#pragma unroll
        for (int m = 0; m < 4; ++m) {
            int boff = (lm << 7) + ((((kq + ks * 4) ^ (lm & 7)) & 7) << 4);
            ah[m] = *(const bf16x8*)((char*)&HB[w][m][0][0] + boff);
            al[m] = *(const bf16x8*)((char*)&HB[w][m][1][0] + boff);
        }
        mfma_ks(w2 + (size_t)ks * 4096, l, ah, al, acc2);
    }

#pragma unroll
    for (int tt = 0; tt < 4; ++tt) {
        float s = 0.f;
#pragma unroll
        for (int m = 0; m < 4; ++m)
#pragma unroll
            for (int r = 0; r < 4; ++r) {
                int rowg = base + (m << 4) + (kq << 2) + r;
                if (rowg < N) s += acc2[m][tt][r];
            }
        s += __shfl_xor(s, 16, 64);
        s += __shfl_xor(s, 32, 64);
        if (l < 16) PS[w][tt * 16 + l] = s;
    }

    char* CW = (char*)&HB[w][0][0][0];
#pragma unroll
    for (int m = 0; m < 4; ++m)
#pragma unroll
        for (int tt = 0; tt < 4; ++tt)
#pragma unroll
            for (int r = 0; r < 4; ++r) {
                int row = (kq << 2) + r;
                int col = (tt << 4) + lm;
                int boff = (row << 8) + ((((col >> 2) ^ (row & 15)) & 15) << 4) + ((col & 3) << 2);
                *(float*)(CW + m * 4096 + boff) = acc2[m][tt][r];
            }
#pragma unroll
    for (int m = 0; m < 4; ++m) {
        int rowg = base + (m << 4) + lm;
        float4 vv[4];
#pragma unroll
        for (int jj = 0; jj < 4; ++jj) {
            int slot = (4 * kq + jj) ^ (lm & 15);
            vv[jj] = *(float4*)(CW + m * 4096 + (lm << 8) + (slot << 4));
        }
        if (rowg < N) {
            float4* dst = (float4*)(nodes_out + (size_t)rowg * DD);
#pragma unroll
            for (int jj = 0; jj < 4; ++jj) dst[kq * 4 + jj] = vv[jj];
            if (write_pk) {
                uint32* pdst = nodes_pk_out + (size_t)rowg * DD + kq * 16;
#pragma unroll
                for (int jj = 0; jj < 4; ++jj) {
                    uint4 o;
                    o.x = packsplit(vv[jj].x);
                    o.y = packsplit(vv[jj].y);
                    o.z = packsplit(vv[jj].z);
                    o.w = packsplit(vv[jj].w);
                    *(uint4*)(pdst + jj * 4) = o;
                }
            }
        }
    }

    __syncthreads();
    if (t < 64) {
        float s = PS[0][t] + PS[1][t] + PS[2][t] + PS[3][t];
        atomicAdd(agg_n + t, s);
    }
}

// ---------------- global update (tiny) ----------------
__global__ void global_kernel(const float* __restrict__ agg_n, const float* __restrict__ agg_e,
                              const float* __restrict__ g_in,
                              const float* __restrict__ Wg1, const float* __restrict__ bg1,
                              const float* __restrict__ Wg2, const float* __restrict__ bg2,
                              float* __restrict__ g_out)
{
    __shared__ float h[64];
    int j = threadIdx.x;
    float a = bg1[j];
    for (int k = 0; k < DD; ++k) a = fmaf(agg_n[k], Wg1[k * DD + j], a);
    for (int k = 0; k < DD; ++k) a = fmaf(agg_e[k], Wg1[(64 + k) * DD + j], a);
    for (int k = 0; k < DD; ++k) a = fmaf(g_in[k],  Wg1[(128 + k) * DD + j], a);
    h[j] = fmaxf(a, 0.f);
    __syncthreads();
    float o = bg2[j];
    for (int k = 0; k < DD; ++k) o = fmaf(h[k], Wg2[k * DD + j], o);
    g_out[j] = o;
}

extern "C" void kernel_launch(void* const* d_in, const int* in_sizes, int n_in,
                              void* d_out, int out_size, void* d_ws, size_t ws_size,
                              hipStream_t stream) {
    const float* nodes0 = (const float*)d_in[0];
    const float* edges0 = (const float*)d_in[1];
    const float* g0     = (const float*)d_in[2];
    const int* senders   = (const int*)d_in[3];
    const int* receivers = (const int*)d_in[4];
    const float* We1 = (const float*)d_in[5];
    const float* be1 = (const float*)d_in[6];
    const float* We2 = (const float*)d_in[7];
    const float* be2 = (const float*)d_in[8];
    const float* Wn1 = (const float*)d_in[9];
    const float* bn1 = (const float*)d_in[10];
    const float* Wn2 = (const float*)d_in[11];
    const float* bn2 = (const float*)d_in[12];
    const float* Wg1 = (const float*)d_in[13];
    const float* bg1 = (const float*)d_in[14];
    const float* Wg2 = (const float*)d_in[15];
    const float* bg2 = (const float*)d_in[16];

    const int N = in_sizes[0] / DD;
    const int E = in_sizes[1] / DD;

    float* out_nodes = (float*)d_out;
    float* out_edges = out_nodes + (size_t)N * DD;
    float* out_g     = out_edges + (size_t)E * DD;

    float* ws = (float*)d_ws;
    float* received = ws;                              // N*64 floats
    float* aggs = received + (size_t)N * DD;           // 512 floats
    float* agg_n = aggs;          // 64
    float* agg_e = aggs + 64;     // 64
    float* b1e   = aggs + 128;    // 64
    float* b1n   = aggs + 192;    // 64
    float* g1    = aggs + 256;    // 64
    float* g2    = aggs + 320;    // 64
    int* counts = (int*)(aggs + 512);                  // N
    int* offs   = counts + N;                          // N+4
    int* cursor = offs + N + 4;                        // N
    int* perm   = cursor + N;                          // E
    uint32* nodes_pk = (uint32*)(perm + E);            // N*64
    unsigned short* we1p = (unsigned short*)(nodes_pk + (size_t)N * DD);  // 24576
    unsigned short* we2p = we1p + 24576;                                  // 8192
    unsigned short* wn1p = we2p + 8192;                                   // 16384
    unsigned short* wn2p = wn1p + 16384;                                  // 8192
    unsigned short* edges_bf = wn2p + 8192;                               // E*64 (bf16)

    size_t need = (size_t)((char*)(edges_bf + (size_t)E * DD) - (char*)d_ws);
    const bool use_bf = (ws_size >= need);

    const int eblocks = (E + 255) / 256;
    const int nblocks = (N + 255) / 256;

    // ---- one-time: CSR build + weight split/swizzle ----
    zero_counts_kernel<<<(N + 255) / 256, 256, 0, stream>>>(counts, N);
    hist_kernel<<<(E + 255) / 256, 256, 0, stream>>>(receivers, counts, E);
    scan_kernel<<<1, 1024, 0, stream>>>(counts, offs, cursor, N);
    scatter_kernel<<<(E + 255) / 256, 256, 0, stream>>>(receivers, cursor, perm, E);
    prep_weights_kernel<<<48, 256, 0, stream>>>(We1, We2, Wn1, Wn2, we1p, we2p, wn1p, wn2p);
    prep_nodes_kernel<<<(N * DD + 255) / 256, 256, 0, stream>>>(nodes0, nodes_pk, N * DD);

    for (int s = 0; s < 3; ++s) {
        const float* esrc_f32 = (s == 0) ? edges0 : out_edges;
        const float* gin  = (s == 0) ? g0 : ((s == 1) ? g1 : g2);
        float* gout       = (s == 2) ? out_g : ((s == 0) ? g1 : g2);
        const bool in_bf  = use_bf && (s > 0);
        const bool out_f32 = (!use_bf) || (s == 2);

        hipMemsetAsync(received, 0, ((size_t)N * DD + 128) * sizeof(float), stream);
        prep_bias_kernel<<<1, 64, 0, stream>>>(gin, We1, be1, Wn1, bn1, b1e, b1n);

        if (in_bf) {
            if (out_f32)
                edge_kernel_t<1, 1><<<eblocks, 256, 0, stream>>>(esrc_f32, edges_bf, nodes_pk,
                    senders, receivers, perm, we1p, b1e, we2p, be2,
                    out_edges, edges_bf, received, agg_e, E);
            else
                edge_kernel_t<1, 0><<<eblocks, 256, 0, stream>>>(esrc_f32, edges_bf, nodes_pk,
                    senders, receivers, perm, we1p, b1e, we2p, be2,
                    out_edges, edges_bf, received, agg_e, E);
        } else {
            if (out_f32)
                edge_kernel_t<0, 1><<<eblocks, 256, 0, stream>>>(esrc_f32, edges_bf, nodes_pk,
                    senders, receivers, perm, we1p, b1e, we2p, be2,
                    out_edges, edges_bf, received, agg_e, E);
            else
                edge_kernel_t<0, 0><<<eblocks, 256, 0, stream>>>(esrc_f32, edges_bf, nodes_pk,
                    senders, receivers, perm, we1p, b1e, we2p, be2,
                    out_edges, edges_bf, received, agg_e, E);
        }

        node_kernel_mfma<<<nblocks, 256, 0, stream>>>(nodes_pk, received, wn1p, b1n, wn2p, bn2,
                                                      out_nodes, nodes_pk, (s < 2) ? 1 : 0,
                                                      agg_n, N);
        global_kernel<<<1, 64, 0, stream>>>(agg_n, agg_e, gin, Wg1, bg1, Wg2, bg2, gout);
    }
}

// Round 7
// 1917.728 us; speedup vs baseline: 1.0669x; 1.0669x over previous
//
#include <hip/hip_runtime.h>

#define DD 64
typedef unsigned int uint32;
typedef unsigned short ushort16;
typedef short bf16x8 __attribute__((ext_vector_type(8)));
typedef float f32x4 __attribute__((ext_vector_type(4)));

__device__ __forceinline__ ushort16 f2bf(float x) {
    uint32 u = __float_as_uint(x);
    uint32 r = (u + 0x7FFFu + ((u >> 16) & 1u)) >> 16;
    return (ushort16)r;
}
__device__ __forceinline__ float bf2f(ushort16 h) {
    return __uint_as_float(((uint32)h) << 16);
}

__device__ __forceinline__ void split8f(const float4& a, const float4& b, bf16x8& ah, bf16x8& al) {
    float xs[8] = {a.x, a.y, a.z, a.w, b.x, b.y, b.z, b.w};
#pragma unroll
    for (int i = 0; i < 8; ++i) {
        ushort16 hi = f2bf(xs[i]);
        ah[i] = (short)hi;
        al[i] = (short)f2bf(xs[i] - bf2f(hi));
    }
}

// 1 k-step (K=32) split-bf16 MFMA over 4 m x 4 n tiles (3-term: exact A)
__device__ __forceinline__ void mfma_ks(const unsigned short* __restrict__ wks, int l,
                                        const bf16x8* ah, const bf16x8* al, f32x4 (*acc)[4]) {
#pragma unroll
    for (int tt = 0; tt < 4; ++tt) {
        bf16x8 bh = *(const bf16x8*)(wks + ((size_t)(tt * 2 + 0) * 64 + l) * 8);
        bf16x8 bl = *(const bf16x8*)(wks + ((size_t)(tt * 2 + 1) * 64 + l) * 8);
#pragma unroll
        for (int m = 0; m < 4; ++m) {
            acc[m][tt] = __builtin_amdgcn_mfma_f32_16x16x32_bf16(ah[m], bh, acc[m][tt], 0, 0, 0);
            acc[m][tt] = __builtin_amdgcn_mfma_f32_16x16x32_bf16(ah[m], bl, acc[m][tt], 0, 0, 0);
            acc[m][tt] = __builtin_amdgcn_mfma_f32_16x16x32_bf16(al[m], bh, acc[m][tt], 0, 0, 0);
        }
    }
}
// hi-only A (2-term: A rounded to bf16, W exact)
__device__ __forceinline__ void mfma_ks_hi(const unsigned short* __restrict__ wks, int l,
                                           const bf16x8* ah, f32x4 (*acc)[4]) {
#pragma unroll
    for (int tt = 0; tt < 4; ++tt) {
        bf16x8 bh = *(const bf16x8*)(wks + ((size_t)(tt * 2 + 0) * 64 + l) * 8);
        bf16x8 bl = *(const bf16x8*)(wks + ((size_t)(tt * 2 + 1) * 64 + l) * 8);
#pragma unroll
        for (int m = 0; m < 4; ++m) {
            acc[m][tt] = __builtin_amdgcn_mfma_f32_16x16x32_bf16(ah[m], bh, acc[m][tt], 0, 0, 0);
            acc[m][tt] = __builtin_amdgcn_mfma_f32_16x16x32_bf16(ah[m], bl, acc[m][tt], 0, 0, 0);
        }
    }
}
// single-m 3-term
__device__ __forceinline__ void mfma_ks1(const unsigned short* __restrict__ wks, int l,
                                         bf16x8 ah, bf16x8 al, f32x4* acc) {
#pragma unroll
    for (int tt = 0; tt < 4; ++tt) {
        bf16x8 bh = *(const bf16x8*)(wks + ((size_t)(tt * 2 + 0) * 64 + l) * 8);
        bf16x8 bl = *(const bf16x8*)(wks + ((size_t)(tt * 2 + 1) * 64 + l) * 8);
        acc[tt] = __builtin_amdgcn_mfma_f32_16x16x32_bf16(ah, bh, acc[tt], 0, 0, 0);
        acc[tt] = __builtin_amdgcn_mfma_f32_16x16x32_bf16(ah, bl, acc[tt], 0, 0, 0);
        acc[tt] = __builtin_amdgcn_mfma_f32_16x16x32_bf16(al, bh, acc[tt], 0, 0, 0);
    }
}

// ---------------- CSR build ----------------
__global__ void zero_counts_kernel(int* __restrict__ counts, int N) {
    int i = blockIdx.x * blockDim.x + threadIdx.x;
    if (i < N) counts[i] = 0;
}
__global__ void hist_kernel(const int* __restrict__ recv, int* __restrict__ counts, int E) {
    int i = blockIdx.x * blockDim.x + threadIdx.x;
    if (i < E) atomicAdd(&counts[recv[i]], 1);
}
__global__ __launch_bounds__(1024) void scan_kernel(const int* __restrict__ counts,
                                                    int* __restrict__ offs,
                                                    int* __restrict__ cursor, int N) {
    __shared__ int sm[1024];
    __shared__ int carryS;
    int t = threadIdx.x;
    if (t == 0) carryS = 0;
    __syncthreads();
    for (int base = 0; base < N; base += 4096) {
        int idx = base + t * 4;
        int x0 = (idx + 0 < N) ? counts[idx + 0] : 0;
        int x1 = (idx + 1 < N) ? counts[idx + 1] : 0;
        int x2 = (idx + 2 < N) ? counts[idx + 2] : 0;
        int x3 = (idx + 3 < N) ? counts[idx + 3] : 0;
        int s1 = x0 + x1, s2 = s1 + x2, s3 = s2 + x3;
        sm[t] = s3;
        __syncthreads();
        for (int d = 1; d < 1024; d <<= 1) {
            int v = (t >= d) ? sm[t - d] : 0;
            __syncthreads();
            sm[t] += v;
            __syncthreads();
        }
        int excl = sm[t] - s3 + carryS;
        if (idx < N)     { offs[idx]     = excl;      cursor[idx]     = excl; }
        if (idx + 1 < N) { offs[idx + 1] = excl + x0; cursor[idx + 1] = excl + x0; }
        if (idx + 2 < N) { offs[idx + 2] = excl + s1; cursor[idx + 2] = excl + s1; }
        if (idx + 3 < N) { offs[idx + 3] = excl + s2; cursor[idx + 3] = excl + s2; }
        int chunkTotal = sm[1023];
        __syncthreads();
        if (t == 0) carryS += chunkTotal;
        __syncthreads();
    }
    if (t == 0) offs[N] = carryS;
}
__global__ void scatter_kernel(const int* __restrict__ recv, int* __restrict__ cursor,
                               int* __restrict__ perm, int* __restrict__ inv, int E) {
    int i = blockIdx.x * blockDim.x + threadIdx.x;
    if (i < E) {
        int p = atomicAdd(&cursor[recv[i]], 1);
        perm[p] = i;
        inv[i] = p;
    }
}

// ---------------- prep: fold g @ W1[g-rows] into effective layer-1 biases --------------
__global__ void prep_bias_kernel(const float* __restrict__ g,
                                 const float* __restrict__ We1, const float* __restrict__ be1,
                                 const float* __restrict__ Wn1, const float* __restrict__ bn1,
                                 float* __restrict__ be1e, float* __restrict__ bn1e) {
    int j = threadIdx.x;
    float a = be1[j];
    float b = bn1[j];
    for (int k = 0; k < DD; ++k) {
        float gk = g[k];
        a = fmaf(gk, We1[(192 + k) * DD + j], a);
        b = fmaf(gk, Wn1[(128 + k) * DD + j], b);
    }
    be1e[j] = a;
    bn1e[j] = b;
}

// ---------------- prep: nodes fp32 -> planar hi/lo bf16 ---------------
__global__ void prep_nodes_kernel(const float* __restrict__ src,
                                  unsigned short* __restrict__ h, unsigned short* __restrict__ l,
                                  int total) {
    int i = blockIdx.x * blockDim.x + threadIdx.x;
    if (i < total) {
        float x = src[i];
        ushort16 hi = f2bf(x);
        h[i] = hi;
        l[i] = f2bf(x - bf2f(hi));
    }
}

// ---------------- prep: edges0 fp32 -> perm-ordered bf16 (once) ---------------
__global__ void prep_edges_kernel(const float* __restrict__ e0, const int* __restrict__ inv,
                                  unsigned short* __restrict__ ebf, int E) {
    int tid = blockIdx.x * blockDim.x + threadIdx.x;
    if (tid < E * 8) {
        int e = tid >> 3, part = tid & 7;
        const float* p = e0 + (size_t)e * DD + part * 8;
        float4 a = *(const float4*)(p);
        float4 b = *(const float4*)(p + 4);
        uint4 o;
        o.x = (uint32)f2bf(a.x) | ((uint32)f2bf(a.y) << 16);
        o.y = (uint32)f2bf(a.z) | ((uint32)f2bf(a.w) << 16);
        o.z = (uint32)f2bf(b.x) | ((uint32)f2bf(b.y) << 16);
        o.w = (uint32)f2bf(b.z) | ((uint32)f2bf(b.w) << 16);
        int ip = inv[e];
        *(uint4*)(ebf + (size_t)ip * DD + part * 8) = o;
    }
}

// ---------------- prep: weights -> hi/lo bf16, pre-swizzled into B-fragment order ------
__device__ __forceinline__ void prep_pack(const float* __restrict__ W, int nks,
                                          unsigned short* __restrict__ dst, int tid) {
    if (tid < nks * 2048) {
        int i = tid & 7, lane = (tid >> 3) & 63, tt = (tid >> 9) & 3, ks = tid >> 11;
        int k = ks * 32 + (lane >> 4) * 8 + i;
        int n = tt * 16 + (lane & 15);
        float x = W[k * DD + n];
        ushort16 hi = f2bf(x);
        ushort16 lo = f2bf(x - bf2f(hi));
        dst[(((ks * 4 + tt) * 2 + 0) * 64 + lane) * 8 + i] = hi;
        dst[(((ks * 4 + tt) * 2 + 1) * 64 + lane) * 8 + i] = lo;
    }
}
__global__ void prep_weights_kernel(const float* __restrict__ We1, const float* __restrict__ We2,
                                    const float* __restrict__ Wn1, const float* __restrict__ Wn2,
                                    unsigned short* __restrict__ we1p, unsigned short* __restrict__ we2p,
                                    unsigned short* __restrict__ wn1p, unsigned short* __restrict__ wn2p) {
    int tid = blockIdx.x * blockDim.x + threadIdx.x;
    prep_pack(We1, 6, we1p, tid);
    prep_pack(We2, 2, we2p, tid);
    prep_pack(Wn1, 4, wn1p, tid);
    prep_pack(Wn2, 2, wn2p, tid);
}

// ======== edge update, receiver-sorted; IN_BF: seq bf16 in; OUT_F32: scatter fp32 out ==
template<int IN_BF, int OUT_F32>
__global__ __launch_bounds__(256, 3) void edge_kernel_t(
    const float* __restrict__ edges_f32, const unsigned short* __restrict__ edges_bf,
    const unsigned short* __restrict__ nodes_h, const unsigned short* __restrict__ nodes_l,
    const int* __restrict__ senders, const int* __restrict__ receivers,
    const int* __restrict__ perm,
    const unsigned short* __restrict__ w1, const float* __restrict__ b1,
    const unsigned short* __restrict__ w2, const float* __restrict__ b2,
    float* __restrict__ eout_f32, unsigned short* __restrict__ eout_bf,
    float* __restrict__ received, float* __restrict__ agg_e, int E)
{
    __shared__ int PE[4][64];
    __shared__ int SID[4][64];
    __shared__ int RID[4][64];
    __shared__ float PS[4][64];
    __shared__ __align__(16) char HB[4][4096];

    const int t = threadIdx.x;
    const int w = t >> 6, l = t & 63;
    const int lm = l & 15, kq = l >> 4;
    const int base = (blockIdx.x << 8) + (w << 6);

    {
        int pos = base + l;
        int pe = perm[min(pos, E - 1)];
        PE[w][l] = pe;
        SID[w][l] = senders[pe];
        RID[w][l] = receivers[pe];
    }

    int pe_m[4], sid_m[4], rid_m[4];
#pragma unroll
    for (int m = 0; m < 4; ++m) {
        pe_m[m]  = PE[w][(m << 4) + lm];
        sid_m[m] = SID[w][(m << 4) + lm];
        rid_m[m] = RID[w][(m << 4) + lm];
    }

    // ---- issue ALL chunk loads up-front (light: 8B fragments) ----
    uint4 rbe[4][2];
    float4 re[4][4];
    if (IN_BF) {
#pragma unroll
        for (int m = 0; m < 4; ++m) {
            int row = min(base + (m << 4) + lm, E - 1);
            const unsigned short* p = edges_bf + (size_t)row * DD + kq * 8;
            rbe[m][0] = *(const uint4*)(p);
            rbe[m][1] = *(const uint4*)(p + 32);
        }
    } else {
#pragma unroll
        for (int m = 0; m < 4; ++m) {
            const float* p = edges_f32 + (size_t)pe_m[m] * DD + kq * 8;
            re[m][0] = *(const float4*)(p);
            re[m][1] = *(const float4*)(p + 4);
            re[m][2] = *(const float4*)(p + 32);
            re[m][3] = *(const float4*)(p + 36);
        }
    }
    // sender: hi-only gather (128B rows)
    uint4 rsh[4][2];
#pragma unroll
    for (int m = 0; m < 4; ++m) {
        const unsigned short* p = nodes_h + (size_t)sid_m[m] * DD + kq * 8;
        rsh[m][0] = *(const uint4*)(p);
        rsh[m][1] = *(const uint4*)(p + 32);
    }
    // receiver: hi+lo (cache-hot)
    uint4 rrh[4][2], rrl[4][2];
#pragma unroll
    for (int m = 0; m < 4; ++m) {
        const unsigned short* ph = nodes_h + (size_t)rid_m[m] * DD + kq * 8;
        const unsigned short* pl = nodes_l + (size_t)rid_m[m] * DD + kq * 8;
        rrh[m][0] = *(const uint4*)(ph);
        rrh[m][1] = *(const uint4*)(ph + 32);
        rrl[m][0] = *(const uint4*)(pl);
        rrl[m][1] = *(const uint4*)(pl + 32);
    }

    f32x4 acc[4][4];
#pragma unroll
    for (int tt = 0; tt < 4; ++tt) {
        float b = b1[tt * 16 + lm];
#pragma unroll
        for (int m = 0; m < 4; ++m) { acc[m][tt][0] = b; acc[m][tt][1] = b; acc[m][tt][2] = b; acc[m][tt][3] = b; }
    }

    // ---- edges chunk (ks 0,1) ----
    if (IN_BF) {
#pragma unroll
        for (int ks2 = 0; ks2 < 2; ++ks2) {
            bf16x8 ah[4];
#pragma unroll
            for (int m = 0; m < 4; ++m) ah[m] = *(bf16x8*)&rbe[m][ks2];
            mfma_ks_hi(w1 + (size_t)ks2 * 4096, l, ah, acc);
        }
    } else {
#pragma unroll
        for (int ks2 = 0; ks2 < 2; ++ks2) {
            bf16x8 ah[4], al[4];
#pragma unroll
            for (int m = 0; m < 4; ++m) split8f(re[m][ks2 * 2], re[m][ks2 * 2 + 1], ah[m], al[m]);
            mfma_ks(w1 + (size_t)ks2 * 4096, l, ah, al, acc);
        }
    }
    // ---- sender chunk (ks 2,3): hi-only ----
#pragma unroll
    for (int ks2 = 0; ks2 < 2; ++ks2) {
        bf16x8 ah[4];
#pragma unroll
        for (int m = 0; m < 4; ++m) ah[m] = *(bf16x8*)&rsh[m][ks2];
        mfma_ks_hi(w1 + (size_t)(2 + ks2) * 4096, l, ah, acc);
    }
    // ---- receiver chunk (ks 4,5): full split ----
#pragma unroll
    for (int ks2 = 0; ks2 < 2; ++ks2) {
        bf16x8 ah[4], al[4];
#pragma unroll
        for (int m = 0; m < 4; ++m) { ah[m] = *(bf16x8*)&rrh[m][ks2]; al[m] = *(bf16x8*)&rrl[m][ks2]; }
        mfma_ks(w1 + (size_t)(4 + ks2) * 4096, l, ah, al, acc);
    }

    // ---- per m-tile: h->LDS, GEMM2, C stage, store + segmented received atomics ----
    float b2v[4];
#pragma unroll
    for (int tt = 0; tt < 4; ++tt) b2v[tt] = b2[tt * 16 + lm];
    float sreg[4] = {0.f, 0.f, 0.f, 0.f};
    char* hh = &HB[w][0];
    char* hl = &HB[w][2048];

#pragma unroll
    for (int m = 0; m < 4; ++m) {
#pragma unroll
        for (int tt = 0; tt < 4; ++tt)
#pragma unroll
            for (int r = 0; r < 4; ++r) {
                int row = (kq << 2) + r;
                int col = (tt << 4) + lm;
                float hv = fmaxf(acc[m][tt][r], 0.f);
                ushort16 hi = f2bf(hv);
                ushort16 lo = f2bf(hv - bf2f(hi));
                int boff = (row << 7) + ((((col >> 3) ^ (row & 7)) & 7) << 4) + ((col & 7) << 1);
                *(unsigned short*)(hh + boff) = hi;
                *(unsigned short*)(hl + boff) = lo;
            }

        f32x4 acc2[4];
#pragma unroll
        for (int tt = 0; tt < 4; ++tt) { acc2[tt][0] = b2v[tt]; acc2[tt][1] = b2v[tt]; acc2[tt][2] = b2v[tt]; acc2[tt][3] = b2v[tt]; }
#pragma unroll
        for (int ks = 0; ks < 2; ++ks) {
            int boff = (lm << 7) + ((((kq + ks * 4) ^ (lm & 7)) & 7) << 4);
            bf16x8 ah = *(const bf16x8*)(hh + boff);
            bf16x8 al = *(const bf16x8*)(hl + boff);
            mfma_ks1(w2 + (size_t)ks * 4096, l, ah, al, acc2);
        }

#pragma unroll
        for (int tt = 0; tt < 4; ++tt)
#pragma unroll
            for (int r = 0; r < 4; ++r) {
                int rowp = base + (m << 4) + (kq << 2) + r;
                if (rowp < E) sreg[tt] += acc2[tt][r];
            }

        // stage C fp32 swizzled
#pragma unroll
        for (int tt = 0; tt < 4; ++tt)
#pragma unroll
            for (int r = 0; r < 4; ++r) {
                int row = (kq << 2) + r;
                int col = (tt << 4) + lm;
                int boff = (row << 8) + ((((col >> 2) ^ (row & 15)) & 15) << 4) + ((col & 3) << 2);
                *(float*)(&HB[w][0] + boff) = acc2[tt][r];
            }

        // readback 16 consecutive cols of row lm
        {
            int rowp = base + (m << 4) + lm;
            float4 vv[4];
#pragma unroll
            for (int jj = 0; jj < 4; ++jj) {
                int slot = (4 * kq + jj) ^ (lm & 15);
                vv[jj] = *(float4*)(&HB[w][0] + (lm << 8) + (slot << 4));
            }
            if (rowp < E) {
                if (OUT_F32) {
                    float4* dst = (float4*)(eout_f32 + (size_t)pe_m[m] * DD);
#pragma unroll
                    for (int jj = 0; jj < 4; ++jj) dst[kq * 4 + jj] = vv[jj];
                } else {
                    uint4 o0, o1;
                    o0.x = (uint32)f2bf(vv[0].x) | ((uint32)f2bf(vv[0].y) << 16);
                    o0.y = (uint32)f2bf(vv[0].z) | ((uint32)f2bf(vv[0].w) << 16);
                    o0.z = (uint32)f2bf(vv[1].x) | ((uint32)f2bf(vv[1].y) << 16);
                    o0.w = (uint32)f2bf(vv[1].z) | ((uint32)f2bf(vv[1].w) << 16);
                    o1.x = (uint32)f2bf(vv[2].x) | ((uint32)f2bf(vv[2].y) << 16);
                    o1.y = (uint32)f2bf(vv[2].z) | ((uint32)f2bf(vv[2].w) << 16);
                    o1.z = (uint32)f2bf(vv[3].x) | ((uint32)f2bf(vv[3].y) << 16);
                    o1.w = (uint32)f2bf(vv[3].z) | ((uint32)f2bf(vv[3].w) << 16);
                    unsigned short* dst = eout_bf + (size_t)rowp * DD + kq * 16;
                    *(uint4*)(dst) = o0;
                    *(uint4*)(dst + 8) = o1;
                }
            }
        }

        // segmented sum over 16 sorted rows -> received atomics (lane = col)
        {
            float run = 0.f;
#pragma unroll
            for (int r = 0; r < 16; ++r) {
                int rowp = base + (m << 4) + r;
                if (rowp < E) {
                    int boff = (r << 8) + ((((l >> 2) ^ (r & 15)) & 15) << 4) + ((l & 3) << 2);
                    float v = *(const float*)(&HB[w][0] + boff);
                    int rid = RID[w][(m << 4) + r];
                    run += v;
                    bool flush;
                    if (r == 15) flush = true;
                    else flush = (rowp + 1 >= E) || (RID[w][(m << 4) + r + 1] != rid);
                    if (flush) {
                        atomicAdd(&received[(size_t)rid * DD + l], run);
                        run = 0.f;
                    }
                }
            }
        }
    }

#pragma unroll
    for (int tt = 0; tt < 4; ++tt) {
        float s = sreg[tt];
        s += __shfl_xor(s, 16, 64);
        s += __shfl_xor(s, 32, 64);
        if (l < 16) PS[w][tt * 16 + l] = s;
    }
    __syncthreads();
    if (t < 64) {
        float s = PS[0][t] + PS[1][t] + PS[2][t] + PS[3][t];
        atomicAdd(agg_e + t, s);
    }
}

// ======================= node update: 256 nodes/block, 64/wave =========================
__global__ __launch_bounds__(256, 2) void node_kernel_mfma(
    const unsigned short* __restrict__ nodes_h_in, const unsigned short* __restrict__ nodes_l_in,
    const float* __restrict__ received,
    const unsigned short* __restrict__ w1, const float* __restrict__ b1,
    const unsigned short* __restrict__ w2, const float* __restrict__ b2,
    float* __restrict__ nodes_out,
    unsigned short* __restrict__ nodes_h_out, unsigned short* __restrict__ nodes_l_out,
    int write_pk, float* __restrict__ agg_n, int N)
{
    __shared__ unsigned short HB[4][4][2][1024];
    __shared__ float PS[4][64];

    const int t = threadIdx.x;
    const int w = t >> 6, l = t & 63;
    const int lm = l & 15, kq = l >> 4;
    const int base = (blockIdx.x << 8) + (w << 6);

    int gi[4];
#pragma unroll
    for (int m = 0; m < 4; ++m) gi[m] = min(base + (m << 4) + lm, N - 1);

    uint4 rnh[4][2], rnl[4][2];
#pragma unroll
    for (int m = 0; m < 4; ++m) {
        const unsigned short* ph = nodes_h_in + (size_t)gi[m] * DD + kq * 8;
        const unsigned short* pl = nodes_l_in + (size_t)gi[m] * DD + kq * 8;
        rnh[m][0] = *(const uint4*)(ph);
        rnh[m][1] = *(const uint4*)(ph + 32);
        rnl[m][0] = *(const uint4*)(pl);
        rnl[m][1] = *(const uint4*)(pl + 32);
    }
    float4 rc[4][4];
#pragma unroll
    for (int m = 0; m < 4; ++m) {
        const float* p = received + (size_t)gi[m] * DD + kq * 8;
        rc[m][0] = *(const float4*)(p);
        rc[m][1] = *(const float4*)(p + 4);
        rc[m][2] = *(const float4*)(p + 32);
        rc[m][3] = *(const float4*)(p + 36);
    }

    f32x4 acc[4][4];
#pragma unroll
    for (int tt = 0; tt < 4; ++tt) {
        float b = b1[tt * 16 + lm];
#pragma unroll
        for (int m = 0; m < 4; ++m) { acc[m][tt][0] = b; acc[m][tt][1] = b; acc[m][tt][2] = b; acc[m][tt][3] = b; }
    }

#pragma unroll
    for (int ks2 = 0; ks2 < 2; ++ks2) {
        bf16x8 ah[4], al[4];
#pragma unroll
        for (int m = 0; m < 4; ++m) { ah[m] = *(bf16x8*)&rnh[m][ks2]; al[m] = *(bf16x8*)&rnl[m][ks2]; }
        mfma_ks(w1 + (size_t)ks2 * 4096, l, ah, al, acc);
    }
#pragma unroll
    for (int ks2 = 0; ks2 < 2; ++ks2) {
        bf16x8 ah[4], al[4];
#pragma unroll
        for (int m = 0; m < 4; ++m) split8f(rc[m][ks2 * 2], rc[m][ks2 * 2 + 1], ah[m], al[m]);
        mfma_ks(w1 + (size_t)(2 + ks2) * 4096, l, ah, al, acc);
    }

#pragma unroll
    for (int m = 0; m < 4; ++m) {
        char* hh = (char*)&HB[w][m][0][0];
        char* hl = (char*)&HB[w][m][1][0];
#pragma unroll
        for (int tt = 0; tt < 4; ++tt)
#pragma unroll
            for (int r = 0; r < 4; ++r) {
                int row = (kq << 2) + r;
                int col = (tt << 4) + lm;
                float hv = fmaxf(acc[m][tt][r], 0.f);
                ushort16 hi = f2bf(hv);
                ushort16 lo = f2bf(hv - bf2f(hi));
                int boff = (row << 7) + ((((col >> 3) ^ (row & 7)) & 7) << 4) + ((col & 7) << 1);
                *(unsigned short*)(hh + boff) = hi;
                *(unsigned short*)(hl + boff) = lo;
            }
    }

    f32x4 acc2[4][4];
#pragma unroll
    for (int tt = 0; tt < 4; ++tt) {
        float b = b2[tt * 16 + lm];
#pragma unroll
        for (int m = 0; m < 4; ++m) { acc2[m][tt][0] = b; acc2[m][tt][1] = b; acc2[m][tt][2] = b; acc2[m][tt][3] = b; }
    }
#pragma unroll
    for (int ks = 0; ks < 2; ++ks) {
        bf16x8 ah[4], al[4];
#pragma unroll
        for (int m = 0; m < 4; ++m) {
            int boff = (lm << 7) + ((((kq + ks * 4) ^ (lm & 7)) & 7) << 4);
            ah[m] = *(const bf16x8*)((char*)&HB[w][m][0][0] + boff);
            al[m] = *(const bf16x8*)((char*)&HB[w][m][1][0] + boff);
        }
        mfma_ks(w2 + (size_t)ks * 4096, l, ah, al, acc2);
    }

#pragma unroll
    for (int tt = 0; tt < 4; ++tt) {
        float s = 0.f;
#pragma unroll
        for (int m = 0; m < 4; ++m)
#pragma unroll
            for (int r = 0; r < 4; ++r) {
                int rowg = base + (m << 4) + (kq << 2) + r;
                if (rowg < N) s += acc2[m][tt][r];
            }
        s += __shfl_xor(s, 16, 64);
        s += __shfl_xor(s, 32, 64);
        if (l < 16) PS[w][tt * 16 + l] = s;
    }

    char* CW = (char*)&HB[w][0][0][0];
#pragma unroll
    for (int m = 0; m < 4; ++m)
#pragma unroll
        for (int tt = 0; tt < 4; ++tt)
#pragma unroll
            for (int r = 0; r < 4; ++r) {
                int row = (kq << 2) + r;
                int col = (tt << 4) + lm;
                int boff = (row << 8) + ((((col >> 2) ^ (row & 15)) & 15) << 4) + ((col & 3) << 2);
                *(float*)(CW + m * 4096 + boff) = acc2[m][tt][r];
            }
#pragma unroll
    for (int m = 0; m < 4; ++m) {
        int rowg = base + (m << 4) + lm;
        float4 vv[4];
#pragma unroll
        for (int jj = 0; jj < 4; ++jj) {
            int slot = (4 * kq + jj) ^ (lm & 15);
            vv[jj] = *(float4*)(CW + m * 4096 + (lm << 8) + (slot << 4));
        }
        if (rowg < N) {
            float4* dst = (float4*)(nodes_out + (size_t)rowg * DD);
#pragma unroll
            for (int jj = 0; jj < 4; ++jj) dst[kq * 4 + jj] = vv[jj];
            if (write_pk) {
                unsigned short* hdst = nodes_h_out + (size_t)rowg * DD + kq * 16;
                unsigned short* ldst = nodes_l_out + (size_t)rowg * DD + kq * 16;
                uint4 oh, ol;
                float xs[16] = {vv[0].x, vv[0].y, vv[0].z, vv[0].w,
                                vv[1].x, vv[1].y, vv[1].z, vv[1].w,
                                vv[2].x, vv[2].y, vv[2].z, vv[2].w,
                                vv[3].x, vv[3].y, vv[3].z, vv[3].w};
                uint32 hw[8], lw[8];
#pragma unroll
                for (int q = 0; q < 8; ++q) {
                    ushort16 h0 = f2bf(xs[2 * q]);
                    ushort16 h1 = f2bf(xs[2 * q + 1]);
                    ushort16 l0 = f2bf(xs[2 * q] - bf2f(h0));
                    ushort16 l1 = f2bf(xs[2 * q + 1] - bf2f(h1));
                    hw[q] = (uint32)h0 | ((uint32)h1 << 16);
                    lw[q] = (uint32)l0 | ((uint32)l1 << 16);
                }
                oh.x = hw[0]; oh.y = hw[1]; oh.z = hw[2]; oh.w = hw[3];
                *(uint4*)(hdst) = oh;
                oh.x = hw[4]; oh.y = hw[5]; oh.z = hw[6]; oh.w = hw[7];
                *(uint4*)(hdst + 8) = oh;
                ol.x = lw[0]; ol.y = lw[1]; ol.z = lw[2]; ol.w = lw[3];
                *(uint4*)(ldst) = ol;
                ol.x = lw[4]; ol.y = lw[5]; ol.z = lw[6]; ol.w = lw[7];
                *(uint4*)(ldst + 8) = ol;
            }
        }
    }

    __syncthreads();
    if (t < 64) {
        float s = PS[0][t] + PS[1][t] + PS[2][t] + PS[3][t];
        atomicAdd(agg_n + t, s);
    }
}

// ---------------- global update (tiny) ----------------
__global__ void global_kernel(const float* __restrict__ agg_n, const float* __restrict__ agg_e,
                              const float* __restrict__ g_in,
                              const float* __restrict__ Wg1, const float* __restrict__ bg1,
                              const float* __restrict__ Wg2, const float* __restrict__ bg2,
                              float* __restrict__ g_out)
{
    __shared__ float h[64];
    int j = threadIdx.x;
    float a = bg1[j];
    for (int k = 0; k < DD; ++k) a = fmaf(agg_n[k], Wg1[k * DD + j], a);
    for (int k = 0; k < DD; ++k) a = fmaf(agg_e[k], Wg1[(64 + k) * DD + j], a);
    for (int k = 0; k < DD; ++k) a = fmaf(g_in[k],  Wg1[(128 + k) * DD + j], a);
    h[j] = fmaxf(a, 0.f);
    __syncthreads();
    float o = bg2[j];
    for (int k = 0; k < DD; ++k) o = fmaf(h[k], Wg2[k * DD + j], o);
    g_out[j] = o;
}

extern "C" void kernel_launch(void* const* d_in, const int* in_sizes, int n_in,
                              void* d_out, int out_size, void* d_ws, size_t ws_size,
                              hipStream_t stream) {
    const float* nodes0 = (const float*)d_in[0];
    const float* edges0 = (const float*)d_in[1];
    const float* g0     = (const float*)d_in[2];
    const int* senders   = (const int*)d_in[3];
    const int* receivers = (const int*)d_in[4];
    const float* We1 = (const float*)d_in[5];
    const float* be1 = (const float*)d_in[6];
    const float* We2 = (const float*)d_in[7];
    const float* be2 = (const float*)d_in[8];
    const float* Wn1 = (const float*)d_in[9];
    const float* bn1 = (const float*)d_in[10];
    const float* Wn2 = (const float*)d_in[11];
    const float* bn2 = (const float*)d_in[12];
    const float* Wg1 = (const float*)d_in[13];
    const float* bg1 = (const float*)d_in[14];
    const float* Wg2 = (const float*)d_in[15];
    const float* bg2 = (const float*)d_in[16];

    const int N = in_sizes[0] / DD;
    const int E = in_sizes[1] / DD;

    float* out_nodes = (float*)d_out;
    float* out_edges = out_nodes + (size_t)N * DD;
    float* out_g     = out_edges + (size_t)E * DD;

    float* ws = (float*)d_ws;
    float* received = ws;                              // N*64 floats
    float* aggs = received + (size_t)N * DD;           // 512 floats
    float* agg_n = aggs;          // 64
    float* agg_e = aggs + 64;     // 64
    float* b1e   = aggs + 128;    // 64
    float* b1n   = aggs + 192;    // 64
    float* g1    = aggs + 256;    // 64
    float* g2    = aggs + 320;    // 64
    int* counts = (int*)(aggs + 512);                  // N
    int* offs   = counts + N;                          // N+4
    int* cursor = offs + N + 4;                        // N
    int* perm   = cursor + N;                          // E
    int* inv    = perm + E;                            // E
    unsigned short* nodes_h = (unsigned short*)(inv + E);                 // N*64
    unsigned short* nodes_l = nodes_h + (size_t)N * DD;                   // N*64
    unsigned short* we1p = nodes_l + (size_t)N * DD;                      // 24576
    unsigned short* we2p = we1p + 24576;                                  // 8192
    unsigned short* wn1p = we2p + 8192;                                   // 16384
    unsigned short* wn2p = wn1p + 16384;                                  // 8192
    unsigned short* edges_bf = wn2p + 8192;                               // E*64 (bf16)

    size_t need = (size_t)((char*)(edges_bf + (size_t)E * DD) - (char*)d_ws);
    const bool use_bf = (ws_size >= need);

    const int eblocks = (E + 255) / 256;
    const int nblocks = (N + 255) / 256;

    // ---- one-time: CSR build + weight/node/edge prep ----
    zero_counts_kernel<<<(N + 255) / 256, 256, 0, stream>>>(counts, N);
    hist_kernel<<<(E + 255) / 256, 256, 0, stream>>>(receivers, counts, E);
    scan_kernel<<<1, 1024, 0, stream>>>(counts, offs, cursor, N);
    scatter_kernel<<<(E + 255) / 256, 256, 0, stream>>>(receivers, cursor, perm, inv, E);
    prep_weights_kernel<<<48, 256, 0, stream>>>(We1, We2, Wn1, Wn2, we1p, we2p, wn1p, wn2p);
    prep_nodes_kernel<<<(N * DD + 255) / 256, 256, 0, stream>>>(nodes0, nodes_h, nodes_l, N * DD);
    if (use_bf)
        prep_edges_kernel<<<(E * 8 + 255) / 256, 256, 0, stream>>>(edges0, inv, edges_bf, E);

    for (int s = 0; s < 3; ++s) {
        const float* esrc_f32 = (s == 0) ? edges0 : out_edges;
        const float* gin  = (s == 0) ? g0 : ((s == 1) ? g1 : g2);
        float* gout       = (s == 2) ? out_g : ((s == 0) ? g1 : g2);

        hipMemsetAsync(received, 0, ((size_t)N * DD + 128) * sizeof(float), stream);
        prep_bias_kernel<<<1, 64, 0, stream>>>(gin, We1, be1, Wn1, bn1, b1e, b1n);

        if (use_bf) {
            if (s == 2)
                edge_kernel_t<1, 1><<<eblocks, 256, 0, stream>>>(esrc_f32, edges_bf, nodes_h, nodes_l,
                    senders, receivers, perm, we1p, b1e, we2p, be2,
                    out_edges, edges_bf, received, agg_e, E);
            else
                edge_kernel_t<1, 0><<<eblocks, 256, 0, stream>>>(esrc_f32, edges_bf, nodes_h, nodes_l,
                    senders, receivers, perm, we1p, b1e, we2p, be2,
                    out_edges, edges_bf, received, agg_e, E);
        } else {
            edge_kernel_t<0, 1><<<eblocks, 256, 0, stream>>>(esrc_f32, edges_bf, nodes_h, nodes_l,
                senders, receivers, perm, we1p, b1e, we2p, be2,
                out_edges, edges_bf, received, agg_e, E);
        }

        node_kernel_mfma<<<nblocks, 256, 0, stream>>>(nodes_h, nodes_l, received,
                                                      wn1p, b1n, wn2p, bn2,
                                                      out_nodes, nodes_h, nodes_l,
                                                      (s < 2) ? 1 : 0, agg_n, N);
        global_kernel<<<1, 64, 0, stream>>>(agg_n, agg_e, gin, Wg1, bg1, Wg2, bg2, gout);
    }
}